// Round 5
// baseline (700.256 us; speedup 1.0000x reference)
//
#include <hip/hip_runtime.h>
#include <cmath>

#define NFEAT_IN 128
#define NFEAT_H 64
#define BN_EPS 1e-5f

typedef unsigned short ushort_t;
typedef unsigned int uint_t;

__device__ inline float b2f(ushort_t u) {
    return __uint_as_float(((uint_t)u) << 16);
}

__device__ inline ushort_t f2b(float f) {
    uint_t x = __float_as_uint(f);
    return (ushort_t)((x + 0x7FFFu + ((x >> 16) & 1u)) >> 16);  // RNE
}

// ---------------- CSR build ----------------

__global__ __launch_bounds__(256) void deg_int_kernel(const int* __restrict__ src,
                                                      const int* __restrict__ dst,
                                                      int* __restrict__ deg_s,
                                                      int* __restrict__ deg_d, int E) {
    int i = blockIdx.x * 256 + threadIdx.x;
    if (i < E) {
        atomicAdd(&deg_s[src[i]], 1);
        atomicAdd(&deg_d[dst[i]], 1);
    }
}

// norms + segment starts via block-level scan (one atomic per block).
// Segments padded to multiples of 8 so int4 loads over col are aligned.
// cursor aliases deg_s (each thread reads deg_s[i] before writing cursor[i]).
__global__ __launch_bounds__(256) void norm_scan_kernel(const int* __restrict__ deg_s,
                                                        const int* __restrict__ deg_d,
                                                        float* __restrict__ norm_s,
                                                        float* __restrict__ norm_d,
                                                        int* __restrict__ start,
                                                        int* __restrict__ cursor,
                                                        int* __restrict__ counter, int N) {
    int tid = threadIdx.x;
    int i = blockIdx.x * 256 + tid;
    int lane = tid & 63, w = tid >> 6;
    int ds = 0, dd = 0;
    if (i < N) { ds = deg_s[i]; dd = deg_d[i]; }
    int pd = (dd + 7) & ~7;  // padded degree

    // wave-inclusive scan of pd
    int x = pd;
#pragma unroll
    for (int off = 1; off < 64; off <<= 1) {
        int y = __shfl_up(x, off, 64);
        if (lane >= off) x += y;
    }
    __shared__ int wsum[4];
    __shared__ int blockbase;
    if (lane == 63) wsum[w] = x;
    __syncthreads();
    if (tid == 0)
        blockbase = atomicAdd(counter, wsum[0] + wsum[1] + wsum[2] + wsum[3]);
    __syncthreads();
    int base = blockbase;
    for (int ww = 0; ww < w; ++ww) base += wsum[ww];
    int st = base + x - pd;  // exclusive scan

    if (i < N) {
        norm_s[i] = rsqrtf((float)(ds > 1 ? ds : 1));
        norm_d[i] = rsqrtf((float)(dd > 1 ? dd : 1));
        start[i] = st;
        cursor[i] = st;
    }
}

__global__ __launch_bounds__(256) void fill_kernel(const int* __restrict__ src,
                                                   const int* __restrict__ dst,
                                                   int* __restrict__ cursor,
                                                   int* __restrict__ col, int E) {
    int e = blockIdx.x * 256 + threadIdx.x;
    if (e < E) {
        int d = dst[e];
        int pos = atomicAdd(&cursor[d], 1);
        col[pos] = src[e];
    }
}

// ---------------- GEMM (1 acc/thread, 4 rows/block), bf16 out ----------------
template <int K, bool IN_BF16, bool FUSE>
__global__ __launch_bounds__(256) void gemm_kernel(const void* __restrict__ xin,
                                                   const float* __restrict__ norm,
                                                   const float* __restrict__ W,
                                                   const float* __restrict__ coef,
                                                   ushort_t* __restrict__ out, int n) {
    __shared__ float sW[K * 64];
    __shared__ float sx[4][K];
    int tid = threadIdx.x;
    int f = tid & 63;
    int r = tid >> 6;
    for (int i = tid; i < K * 16; i += 256)
        ((float4*)sW)[i] = ((const float4*)W)[i];
    int row0 = blockIdx.x * 4;

    if constexpr (IN_BF16) {
        const ushort_t* x = (const ushort_t*)xin;
        if (tid < 64) {
            int rr = tid >> 4;
            int c4 = tid & 15;
            int row = row0 + rr;
            if (row < n) {
                uint2 u = ((const uint2*)(x + (long long)row * 64))[c4];
                int k = c4 * 4;
                float f0 = __uint_as_float(u.x << 16);
                float f1 = __uint_as_float(u.x & 0xFFFF0000u);
                float f2 = __uint_as_float(u.y << 16);
                float f3 = __uint_as_float(u.y & 0xFFFF0000u);
                if constexpr (FUSE) {
                    f0 = f0 * coef[k] + coef[64 + k];
                    f1 = f1 * coef[k + 1] + coef[64 + k + 1];
                    f2 = f2 * coef[k + 2] + coef[64 + k + 2];
                    f3 = f3 * coef[k + 3] + coef[64 + k + 3];
                }
                float nv = norm[row];
                sx[rr][k] = f0 * nv;
                sx[rr][k + 1] = f1 * nv;
                sx[rr][k + 2] = f2 * nv;
                sx[rr][k + 3] = f3 * nv;
            }
        }
    } else {
        const float* x = (const float*)xin;
        constexpr int V4 = K / 4;
        for (int i = tid; i < 4 * V4; i += 256) {
            int rr = i / V4, c4 = i - rr * V4;
            int row = row0 + rr;
            if (row < n) {
                float4 v = ((const float4*)(x + (long long)row * K))[c4];
                float nv = norm[row];
                v.x *= nv; v.y *= nv; v.z *= nv; v.w *= nv;
                ((float4*)sx[rr])[c4] = v;
            }
        }
    }
    __syncthreads();

    int row = row0 + r;
    if (row >= n) return;
    float acc = 0.f;
#pragma unroll
    for (int k = 0; k < K; ++k) acc = fmaf(sx[r][k], sW[k * 64 + f], acc);
    out[(long long)row * 64 + f] = f2b(acc);
}

// ---------------- gather-aggregate v3: thread=feat, 16 rows in flight ----------------
template <bool OUT_BF16>
__global__ __launch_bounds__(256) void agg_fused_kernel(const ushort_t* __restrict__ h,
                                                        const int* __restrict__ start,
                                                        const int* __restrict__ degd,
                                                        const int* __restrict__ col,
                                                        const float* __restrict__ normd,
                                                        const float* __restrict__ bias,
                                                        void* __restrict__ outp,
                                                        float* __restrict__ stats, int N) {
    int tid = threadIdx.x;
    int f = tid & 63;
    int w = tid >> 6;
    float b = bias[f];
    float sum = 0.f, sq = 0.f;

    for (int node = blockIdx.x * 4 + w; node < N; node += gridDim.x * 4) {
        int s0 = start[node];
        int d = degd[node];
        float acc = 0.f;
        int k = 0;
        for (; k + 16 <= d; k += 16) {
            int4 ca = *(const int4*)(col + s0 + k);
            int4 cb = *(const int4*)(col + s0 + k + 4);
            int4 cc = *(const int4*)(col + s0 + k + 8);
            int4 cd = *(const int4*)(col + s0 + k + 12);
            float v0 = b2f(h[(long long)ca.x * 64 + f]);
            float v1 = b2f(h[(long long)ca.y * 64 + f]);
            float v2 = b2f(h[(long long)ca.z * 64 + f]);
            float v3 = b2f(h[(long long)ca.w * 64 + f]);
            float v4 = b2f(h[(long long)cb.x * 64 + f]);
            float v5 = b2f(h[(long long)cb.y * 64 + f]);
            float v6 = b2f(h[(long long)cb.z * 64 + f]);
            float v7 = b2f(h[(long long)cb.w * 64 + f]);
            float v8 = b2f(h[(long long)cc.x * 64 + f]);
            float v9 = b2f(h[(long long)cc.y * 64 + f]);
            float va = b2f(h[(long long)cc.z * 64 + f]);
            float vb = b2f(h[(long long)cc.w * 64 + f]);
            float vc = b2f(h[(long long)cd.x * 64 + f]);
            float vd = b2f(h[(long long)cd.y * 64 + f]);
            float ve = b2f(h[(long long)cd.z * 64 + f]);
            float vf = b2f(h[(long long)cd.w * 64 + f]);
            acc += (((v0 + v1) + (v2 + v3)) + ((v4 + v5) + (v6 + v7))) +
                   (((v8 + v9) + (va + vb)) + ((vc + vd) + (ve + vf)));
        }
        for (; k + 8 <= d; k += 8) {
            int4 ca = *(const int4*)(col + s0 + k);
            int4 cb = *(const int4*)(col + s0 + k + 4);
            float v0 = b2f(h[(long long)ca.x * 64 + f]);
            float v1 = b2f(h[(long long)ca.y * 64 + f]);
            float v2 = b2f(h[(long long)ca.z * 64 + f]);
            float v3 = b2f(h[(long long)ca.w * 64 + f]);
            float v4 = b2f(h[(long long)cb.x * 64 + f]);
            float v5 = b2f(h[(long long)cb.y * 64 + f]);
            float v6 = b2f(h[(long long)cb.z * 64 + f]);
            float v7 = b2f(h[(long long)cb.w * 64 + f]);
            acc += ((v0 + v1) + (v2 + v3)) + ((v4 + v5) + (v6 + v7));
        }
        for (; k < d; ++k) acc += b2f(h[(long long)col[s0 + k] * 64 + f]);

        float v = acc * normd[node] + b;
        v = v > 0.f ? v : expm1f(v);
        if constexpr (OUT_BF16)
            ((ushort_t*)outp)[(long long)node * 64 + f] = f2b(v);
        else
            ((float*)outp)[(long long)node * 64 + f] = v;
        sum += v;
        sq += v * v;
    }

    __shared__ float ssum[256], ssq[256];
    ssum[tid] = sum;
    ssq[tid] = sq;
    __syncthreads();
    if (tid < 64) {
        float s = ssum[tid] + ssum[tid + 64] + ssum[tid + 128] + ssum[tid + 192];
        float q = ssq[tid] + ssq[tid + 64] + ssq[tid + 128] + ssq[tid + 192];
        atomicAdd(&stats[tid], s);
        atomicAdd(&stats[64 + tid], q);
    }
}

__global__ __launch_bounds__(64) void bn_finalize(const float* __restrict__ stats,
                                                  const float* __restrict__ gamma,
                                                  const float* __restrict__ beta,
                                                  float* __restrict__ coef, float inv_n) {
    int f = threadIdx.x;
    float mean = stats[f] * inv_n;
    float var = stats[64 + f] * inv_n - mean * mean;
    float a = gamma[f] * rsqrtf(var + BN_EPS);
    coef[f] = a;
    coef[64 + f] = beta[f] - mean * a;
}

// in-place BN apply, float4 (64 feats = 16 float4 per row)
__global__ __launch_bounds__(256) void bn_apply4(float4* __restrict__ io,
                                                 const float* __restrict__ coef,
                                                 long long total4) {
    long long i = (long long)blockIdx.x * 256 + threadIdx.x;
    if (i >= total4) return;
    int k = (int)((i & 15) << 2);
    float4 v = io[i];
    v.x = v.x * coef[k] + coef[64 + k];
    v.y = v.y * coef[k + 1] + coef[64 + k + 1];
    v.z = v.z * coef[k + 2] + coef[64 + k + 2];
    v.w = v.w * coef[k + 3] + coef[64 + k + 3];
    io[i] = v;
}

// ---------------- launch ----------------

extern "C" void kernel_launch(void* const* d_in, const int* in_sizes, int n_in,
                              void* d_out, int out_size, void* d_ws, size_t ws_size,
                              hipStream_t stream) {
    const float* features = (const float*)d_in[0];
    const float* W1 = (const float*)d_in[1];
    const float* b1 = (const float*)d_in[2];
    const float* gamma1 = (const float*)d_in[3];
    const float* beta1 = (const float*)d_in[4];
    const float* W2 = (const float*)d_in[5];
    const float* b2 = (const float*)d_in[6];
    const float* gamma2 = (const float*)d_in[7];
    const float* beta2 = (const float*)d_in[8];
    const int* src = (const int*)d_in[9];
    const int* dst = (const int*)d_in[10];
    int N = in_sizes[0] / NFEAT_IN;
    int E = in_sizes[9];

    float inv_n = 1.0f / (float)N;
    long long tot = (long long)N * 64;
    int eblk256 = (E + 255) / 256;
    int nblk256 = (N + 255) / 256;
    int gblk = (N + 3) / 4;
    long long tot4 = tot / 4;
    int t4blk = (int)((tot4 + 255) / 256);

    // workspace: [ints: deg_s|deg_d|start|col(E+8N)|counter][floats: norm_s|norm_d|stats|coef][bf16 hA][bf16 oB]
    long long colcap = (long long)E + 8LL * N;
    long long int_count = 3LL * N + colcap + 1;
    long long int_total = (int_count + 3) & ~3LL;
    long long flt_count = ((2LL * N + 256) + 3) & ~3LL;

    int* ip = (int*)d_ws;
    int* deg_s = ip;                 // reused as cursor
    int* deg_d = ip + N;
    int* startv = ip + 2LL * N;
    int* col = ip + 3LL * N;
    int* counter = ip + 3LL * N + colcap;
    float* fp = (float*)(ip + int_total);
    float* norm_s = fp;
    float* norm_d = fp + N;
    float* stats = fp + 2LL * N;
    float* coef = stats + 128;
    ushort_t* hA = (ushort_t*)(fp + flt_count);   // N*64 bf16
    ushort_t* oB = hA + tot;                      // N*64 bf16

    // CSR build
    hipMemsetAsync(deg_s, 0, sizeof(int) * 2LL * N, stream);
    hipMemsetAsync(counter, 0, sizeof(int), stream);
    deg_int_kernel<<<eblk256, 256, 0, stream>>>(src, dst, deg_s, deg_d, E);
    norm_scan_kernel<<<nblk256, 256, 0, stream>>>(deg_s, deg_d, norm_s, norm_d,
                                                  startv, /*cursor=*/deg_s, counter, N);
    fill_kernel<<<eblk256, 256, 0, stream>>>(src, dst, /*cursor=*/deg_s, col, E);

    // ---- layer 1 ----
    gemm_kernel<NFEAT_IN, false, false><<<gblk, 256, 0, stream>>>(features, norm_s, W1,
                                                                  nullptr, hA, N);
    hipMemsetAsync(stats, 0, sizeof(float) * 128, stream);
    agg_fused_kernel<true><<<2048, 256, 0, stream>>>(hA, startv, deg_d, col, norm_d, b1,
                                                     oB, stats, N);
    bn_finalize<<<1, 64, 0, stream>>>(stats, gamma1, beta1, coef, inv_n);

    // ---- layer 2 (BN1 fused into gemm input) ----
    gemm_kernel<NFEAT_H, true, true><<<gblk, 256, 0, stream>>>(oB, norm_s, W2,
                                                               coef, hA, N);
    hipMemsetAsync(stats, 0, sizeof(float) * 128, stream);
    agg_fused_kernel<false><<<2048, 256, 0, stream>>>(hA, startv, deg_d, col, norm_d, b2,
                                                      d_out, stats, N);
    bn_finalize<<<1, 64, 0, stream>>>(stats, gamma2, beta2, coef, inv_n);
    bn_apply4<<<t4blk, 256, 0, stream>>>((float4*)d_out, coef, tot4);
}

// Round 6
// 645.717 us; speedup vs baseline: 1.0845x; 1.0845x over previous
//
#include <hip/hip_runtime.h>
#include <cmath>

#define NFEAT_IN 128
#define NFEAT_H 64
#define BN_EPS 1e-5f

typedef unsigned short ushort_t;
typedef unsigned int uint_t;

__device__ inline float b2f(ushort_t u) {
    return __uint_as_float(((uint_t)u) << 16);
}

__device__ inline ushort_t f2b(float f) {
    uint_t x = __float_as_uint(f);
    return (ushort_t)((x + 0x7FFFu + ((x >> 16) & 1u)) >> 16);  // RNE
}

// ---------------- CSR build ----------------

__global__ __launch_bounds__(256) void deg_int_kernel(const int* __restrict__ src,
                                                      const int* __restrict__ dst,
                                                      int* __restrict__ deg_s,
                                                      int* __restrict__ deg_d, int E) {
    int i = blockIdx.x * 256 + threadIdx.x;
    if (i < E) {
        atomicAdd(&deg_s[src[i]], 1);
        atomicAdd(&deg_d[dst[i]], 1);
    }
}

// norms + segment starts via block-level scan (one atomic per block).
// Segments padded to multiples of 8. cursor aliases deg_s.
// Also zeroes stats for layer 1 (block 0).
__global__ __launch_bounds__(256) void norm_scan_kernel(const int* __restrict__ deg_s,
                                                        const int* __restrict__ deg_d,
                                                        float* __restrict__ norm_s,
                                                        float* __restrict__ norm_d,
                                                        int* __restrict__ start,
                                                        int* __restrict__ cursor,
                                                        int* __restrict__ counter,
                                                        float* __restrict__ stats, int N) {
    int tid = threadIdx.x;
    int i = blockIdx.x * 256 + tid;
    if (blockIdx.x == 0 && tid < 128) stats[tid] = 0.f;
    int lane = tid & 63, w = tid >> 6;
    int ds = 0, dd = 0;
    if (i < N) { ds = deg_s[i]; dd = deg_d[i]; }
    int pd = (dd + 7) & ~7;  // padded degree

    // wave-inclusive scan of pd
    int x = pd;
#pragma unroll
    for (int off = 1; off < 64; off <<= 1) {
        int y = __shfl_up(x, off, 64);
        if (lane >= off) x += y;
    }
    __shared__ int wsum[4];
    __shared__ int blockbase;
    if (lane == 63) wsum[w] = x;
    __syncthreads();
    if (tid == 0)
        blockbase = atomicAdd(counter, wsum[0] + wsum[1] + wsum[2] + wsum[3]);
    __syncthreads();
    int base = blockbase;
    for (int ww = 0; ww < w; ++ww) base += wsum[ww];
    int st = base + x - pd;  // exclusive scan

    if (i < N) {
        norm_s[i] = rsqrtf((float)(ds > 1 ? ds : 1));
        norm_d[i] = rsqrtf((float)(dd > 1 ? dd : 1));
        start[i] = st;
        cursor[i] = st;
    }
}

__global__ __launch_bounds__(256) void fill_kernel(const int* __restrict__ src,
                                                   const int* __restrict__ dst,
                                                   int* __restrict__ cursor,
                                                   int* __restrict__ col, int E) {
    int e = blockIdx.x * 256 + threadIdx.x;
    if (e < E) {
        int d = dst[e];
        int pos = atomicAdd(&cursor[d], 1);
        col[pos] = src[e];
    }
}

// ---------------- GEMM: 32 rows/block (8 tiles x 4 rows), W staged once ----------------
// out[row][f] = sum_k xhat[row][k]*norm[row] * W[k][f], bf16 out.
template <int K, bool IN_BF16, bool FUSE>
__global__ __launch_bounds__(256) void gemm_kernel(const void* __restrict__ xin,
                                                   const float* __restrict__ norm,
                                                   const float* __restrict__ W,
                                                   const float* __restrict__ coef,
                                                   ushort_t* __restrict__ out, int n) {
    __shared__ float sW[K * 64];
    __shared__ float sx[4][K];
    int tid = threadIdx.x;
    int f = tid & 63;
    int r = tid >> 6;
    for (int i = tid; i < K * 16; i += 256)
        ((float4*)sW)[i] = ((const float4*)W)[i];
    int base = blockIdx.x * 32;

#pragma unroll 1
    for (int t = 0; t < 8; ++t) {
        int row0 = base + t * 4;
        __syncthreads();  // t=0: sW ready; t>0: previous compute done before sx overwrite

        if constexpr (IN_BF16) {
            const ushort_t* x = (const ushort_t*)xin;
            if (tid < 64) {
                int rr = tid >> 4;
                int c4 = tid & 15;
                int row = row0 + rr;
                if (row < n) {
                    uint2 u = ((const uint2*)(x + (long long)row * 64))[c4];
                    int k = c4 * 4;
                    float f0 = __uint_as_float(u.x << 16);
                    float f1 = __uint_as_float(u.x & 0xFFFF0000u);
                    float f2 = __uint_as_float(u.y << 16);
                    float f3 = __uint_as_float(u.y & 0xFFFF0000u);
                    if constexpr (FUSE) {
                        f0 = f0 * coef[k] + coef[64 + k];
                        f1 = f1 * coef[k + 1] + coef[64 + k + 1];
                        f2 = f2 * coef[k + 2] + coef[64 + k + 2];
                        f3 = f3 * coef[k + 3] + coef[64 + k + 3];
                    }
                    float nv = norm[row];
                    sx[rr][k] = f0 * nv;
                    sx[rr][k + 1] = f1 * nv;
                    sx[rr][k + 2] = f2 * nv;
                    sx[rr][k + 3] = f3 * nv;
                }
            }
        } else {
            const float* x = (const float*)xin;
            constexpr int V4 = K / 4;
            for (int i = tid; i < 4 * V4; i += 256) {
                int rr = i / V4, c4 = i - rr * V4;
                int row = row0 + rr;
                if (row < n) {
                    float4 v = ((const float4*)(x + (long long)row * K))[c4];
                    float nv = norm[row];
                    v.x *= nv; v.y *= nv; v.z *= nv; v.w *= nv;
                    ((float4*)sx[rr])[c4] = v;
                }
            }
        }
        __syncthreads();

        int row = row0 + r;
        if (row < n) {
            float acc = 0.f;
#pragma unroll
            for (int k = 0; k < K; ++k) acc = fmaf(sx[r][k], sW[k * 64 + f], acc);
            out[(long long)row * 64 + f] = f2b(acc);
        }
    }
}

// ---------------- gather-aggregate (R4-v2 proven config: uint4, 8 lane-groups) ----------------
template <bool OUT_BF16>
__global__ __launch_bounds__(256) void agg_fused_kernel(const ushort_t* __restrict__ h,
                                                        const int* __restrict__ start,
                                                        const int* __restrict__ degd,
                                                        const int* __restrict__ col,
                                                        const float* __restrict__ normd,
                                                        const float* __restrict__ bias,
                                                        void* __restrict__ outp,
                                                        float* __restrict__ stats, int N) {
    int tid = threadIdx.x;
    int w = tid >> 6;
    int lane = tid & 63;
    int g = lane >> 3;
    int j = lane & 7;

    float bb[8];
#pragma unroll
    for (int i = 0; i < 8; ++i) bb[i] = bias[j * 8 + i];

    float sum[8], sq[8];
#pragma unroll
    for (int i = 0; i < 8; ++i) { sum[i] = 0.f; sq[i] = 0.f; }

    for (int node = blockIdx.x * 4 + w; node < N; node += gridDim.x * 4) {
        int s0 = start[node];
        int d = degd[node];
        float acc[8];
#pragma unroll
        for (int i = 0; i < 8; ++i) acc[i] = 0.f;

        int k = 0;
        for (; k + 16 <= d; k += 16) {
            int c0 = col[s0 + k + g];
            int c1 = col[s0 + k + 8 + g];
            uint4 a = ((const uint4*)(h + (long long)c0 * 64))[j];
            uint4 b = ((const uint4*)(h + (long long)c1 * 64))[j];
            acc[0] += __uint_as_float(a.x << 16);
            acc[1] += __uint_as_float(a.x & 0xFFFF0000u);
            acc[2] += __uint_as_float(a.y << 16);
            acc[3] += __uint_as_float(a.y & 0xFFFF0000u);
            acc[4] += __uint_as_float(a.z << 16);
            acc[5] += __uint_as_float(a.z & 0xFFFF0000u);
            acc[6] += __uint_as_float(a.w << 16);
            acc[7] += __uint_as_float(a.w & 0xFFFF0000u);
            acc[0] += __uint_as_float(b.x << 16);
            acc[1] += __uint_as_float(b.x & 0xFFFF0000u);
            acc[2] += __uint_as_float(b.y << 16);
            acc[3] += __uint_as_float(b.y & 0xFFFF0000u);
            acc[4] += __uint_as_float(b.z << 16);
            acc[5] += __uint_as_float(b.z & 0xFFFF0000u);
            acc[6] += __uint_as_float(b.w << 16);
            acc[7] += __uint_as_float(b.w & 0xFFFF0000u);
        }
        for (; k + 8 <= d; k += 8) {
            int c0 = col[s0 + k + g];
            uint4 a = ((const uint4*)(h + (long long)c0 * 64))[j];
            acc[0] += __uint_as_float(a.x << 16);
            acc[1] += __uint_as_float(a.x & 0xFFFF0000u);
            acc[2] += __uint_as_float(a.y << 16);
            acc[3] += __uint_as_float(a.y & 0xFFFF0000u);
            acc[4] += __uint_as_float(a.z << 16);
            acc[5] += __uint_as_float(a.z & 0xFFFF0000u);
            acc[6] += __uint_as_float(a.w << 16);
            acc[7] += __uint_as_float(a.w & 0xFFFF0000u);
        }
        if (k < d) {
            int idx = k + g;
            if (idx < d) {
                int c0 = col[s0 + idx];
                uint4 a = ((const uint4*)(h + (long long)c0 * 64))[j];
                acc[0] += __uint_as_float(a.x << 16);
                acc[1] += __uint_as_float(a.x & 0xFFFF0000u);
                acc[2] += __uint_as_float(a.y << 16);
                acc[3] += __uint_as_float(a.y & 0xFFFF0000u);
                acc[4] += __uint_as_float(a.z << 16);
                acc[5] += __uint_as_float(a.z & 0xFFFF0000u);
                acc[6] += __uint_as_float(a.w << 16);
                acc[7] += __uint_as_float(a.w & 0xFFFF0000u);
            }
        }

        // reduce across g (lane bits 3,4,5)
#pragma unroll
        for (int i = 0; i < 8; ++i) {
            acc[i] += __shfl_xor(acc[i], 8, 64);
            acc[i] += __shfl_xor(acc[i], 16, 64);
            acc[i] += __shfl_xor(acc[i], 32, 64);
        }

        if (g == 0) {
            float nv = normd[node];
            float v[8];
#pragma unroll
            for (int i = 0; i < 8; ++i) {
                float t = acc[i] * nv + bb[i];
                t = t > 0.f ? t : expm1f(t);
                v[i] = t;
                sum[i] += t;
                sq[i] += t * t;
            }
            if constexpr (OUT_BF16) {
                uint4 p;
                p.x = ((uint_t)f2b(v[1]) << 16) | f2b(v[0]);
                p.y = ((uint_t)f2b(v[3]) << 16) | f2b(v[2]);
                p.z = ((uint_t)f2b(v[5]) << 16) | f2b(v[4]);
                p.w = ((uint_t)f2b(v[7]) << 16) | f2b(v[6]);
                ((uint4*)((ushort_t*)outp + (long long)node * 64))[j] = p;
            } else {
                float* o = (float*)outp + (long long)node * 64 + j * 8;
                ((float4*)o)[0] = make_float4(v[0], v[1], v[2], v[3]);
                ((float4*)o)[1] = make_float4(v[4], v[5], v[6], v[7]);
            }
        }
    }

    __shared__ float ssum[4][64];
    __shared__ float ssq[4][64];
    if (g == 0) {
#pragma unroll
        for (int i = 0; i < 8; ++i) {
            ssum[w][j * 8 + i] = sum[i];
            ssq[w][j * 8 + i] = sq[i];
        }
    }
    __syncthreads();
    if (tid < 64) {
        float s = ssum[0][tid] + ssum[1][tid] + ssum[2][tid] + ssum[3][tid];
        float q = ssq[0][tid] + ssq[1][tid] + ssq[2][tid] + ssq[3][tid];
        atomicAdd(&stats[tid], s);
        atomicAdd(&stats[64 + tid], q);
    }
}

// Computes coef from stats, then zeroes stats for the next layer.
__global__ __launch_bounds__(64) void bn_finalize(float* __restrict__ stats,
                                                  const float* __restrict__ gamma,
                                                  const float* __restrict__ beta,
                                                  float* __restrict__ coef, float inv_n) {
    int f = threadIdx.x;
    float mean = stats[f] * inv_n;
    float var = stats[64 + f] * inv_n - mean * mean;
    float a = gamma[f] * rsqrtf(var + BN_EPS);
    coef[f] = a;
    coef[64 + f] = beta[f] - mean * a;
    stats[f] = 0.f;
    stats[64 + f] = 0.f;
}

// in-place BN apply, float4 (64 feats = 16 float4 per row)
__global__ __launch_bounds__(256) void bn_apply4(float4* __restrict__ io,
                                                 const float* __restrict__ coef,
                                                 long long total4) {
    long long i = (long long)blockIdx.x * 256 + threadIdx.x;
    if (i >= total4) return;
    int k = (int)((i & 15) << 2);
    float4 v = io[i];
    v.x = v.x * coef[k] + coef[64 + k];
    v.y = v.y * coef[k + 1] + coef[64 + k + 1];
    v.z = v.z * coef[k + 2] + coef[64 + k + 2];
    v.w = v.w * coef[k + 3] + coef[64 + k + 3];
    io[i] = v;
}

// ---------------- launch ----------------

extern "C" void kernel_launch(void* const* d_in, const int* in_sizes, int n_in,
                              void* d_out, int out_size, void* d_ws, size_t ws_size,
                              hipStream_t stream) {
    const float* features = (const float*)d_in[0];
    const float* W1 = (const float*)d_in[1];
    const float* b1 = (const float*)d_in[2];
    const float* gamma1 = (const float*)d_in[3];
    const float* beta1 = (const float*)d_in[4];
    const float* W2 = (const float*)d_in[5];
    const float* b2 = (const float*)d_in[6];
    const float* gamma2 = (const float*)d_in[7];
    const float* beta2 = (const float*)d_in[8];
    const int* src = (const int*)d_in[9];
    const int* dst = (const int*)d_in[10];
    int N = in_sizes[0] / NFEAT_IN;
    int E = in_sizes[9];

    float inv_n = 1.0f / (float)N;
    long long tot = (long long)N * 64;
    int eblk256 = (E + 255) / 256;
    int nblk256 = (N + 255) / 256;
    int gblk = (N + 31) / 32;
    long long tot4 = tot / 4;
    int t4blk = (int)((tot4 + 255) / 256);

    // workspace layout (ints, then 16B-aligned floats, then bf16 buffers)
    // [deg_s(N) | deg_d(N) | counter(+pad 4) | startv(N) | col(E+8N)] [norm_s|norm_d|stats|coef] [hA][oB]
    long long colcap = (long long)E + 8LL * N;
    long long int_total = (3LL * N + 4 + colcap + 3) & ~3LL;
    long long flt_count = ((2LL * N + 256) + 3) & ~3LL;

    int* ip = (int*)d_ws;
    int* deg_s = ip;                 // reused as cursor
    int* deg_d = ip + N;
    int* counter = ip + 2LL * N;
    int* startv = ip + 2LL * N + 4;
    int* col = ip + 3LL * N + 4;
    float* fp = (float*)(ip + int_total);
    float* norm_s = fp;
    float* norm_d = fp + N;
    float* stats = fp + 2LL * N;
    float* coef = stats + 128;
    ushort_t* hA = (ushort_t*)(fp + flt_count);   // N*64 bf16
    ushort_t* oB = hA + tot;                      // N*64 bf16

    // CSR build (single memset covers deg_s, deg_d, counter)
    hipMemsetAsync(deg_s, 0, sizeof(int) * (2LL * N + 4), stream);
    deg_int_kernel<<<eblk256, 256, 0, stream>>>(src, dst, deg_s, deg_d, E);
    norm_scan_kernel<<<nblk256, 256, 0, stream>>>(deg_s, deg_d, norm_s, norm_d,
                                                  startv, /*cursor=*/deg_s, counter,
                                                  stats, N);
    fill_kernel<<<eblk256, 256, 0, stream>>>(src, dst, /*cursor=*/deg_s, col, E);

    // ---- layer 1 ----
    gemm_kernel<NFEAT_IN, false, false><<<gblk, 256, 0, stream>>>(features, norm_s, W1,
                                                                  nullptr, hA, N);
    agg_fused_kernel<true><<<2048, 256, 0, stream>>>(hA, startv, deg_d, col, norm_d, b1,
                                                     oB, stats, N);
    bn_finalize<<<1, 64, 0, stream>>>(stats, gamma1, beta1, coef, inv_n);

    // ---- layer 2 (BN1 fused into gemm input) ----
    gemm_kernel<NFEAT_H, true, true><<<gblk, 256, 0, stream>>>(oB, norm_s, W2,
                                                               coef, hA, N);
    agg_fused_kernel<false><<<2048, 256, 0, stream>>>(hA, startv, deg_d, col, norm_d, b2,
                                                      d_out, stats, N);
    bn_finalize<<<1, 64, 0, stream>>>(stats, gamma2, beta2, coef, inv_n);
    bn_apply4<<<t4blk, 256, 0, stream>>>((float4*)d_out, coef, tot4);
}